// Round 8
// baseline (63.627 us; speedup 1.0000x reference)
//
#include <hip/hip_runtime.h>

#define BINS 30
#define BLOCK 256
#define GRID 768            // 3 blocks/CU, 12 waves/CU (R4-like hiding)
#define GSTRIDE 32          // one 128B cache line per global accumulator slot
#define KSTEP 4096.0f

// NOTE: __builtin_amdgcn_cvt_pkrtz returns __fp16 ext_vector(2) — match it.
typedef __fp16 f16x2 __attribute__((ext_vector_type(2)));

__device__ __forceinline__ float fast_exp2(float x){ return __builtin_amdgcn_exp2f(x); }
__device__ __forceinline__ float fast_log2(float x){ return __builtin_amdgcn_logf(x); }

#define LOG2E 1.4426950408889634f
#define LN2   0.6931471805599453f

// Cumulative-threshold formulation (no LDS, no atomics in hot loop):
//   y = t ? -x : x;  g = sigmoid(y);  bin(y) = #{k>=1 : y >= logit(k/30)}
//   bce = max(y,0) + log1p(exp(-|y|))
// Slot k (k=0..29) accumulates over elements with y >= thr[k]:
//   C_k (count) and S_k (bce sum); thr[0] = -inf so slot 0 = totals.
// step(y - thr) computed as ONE `v_add_f32 dst, sConst, yk clamp` where
// yk = y*4096 and sConst = -4096*thr (soft zone 2.4e-4 wide — negligible).
// Two slots accumulate per packed f16 op (counts are exact ints <= ~84).
__global__ __launch_bounds__(BLOCK) void ghm_pass1(
    const float4* __restrict__ preds4, const float4* __restrict__ targets4,
    long n4, long n_total,
    float* __restrict__ gCnt, float* __restrict__ gSum)   // padded slots 0..29
{
    // compile-time -4096*thr table (constant-folded, hoisted to SGPRs)
    const float nthr[30] = {
        8.192e29f,
        KSTEP*3.3673323f,  KSTEP*2.6390573f,  KSTEP*2.1972246f,  KSTEP*1.8718022f,
        KSTEP*1.6094379f,  KSTEP*1.3862944f,  KSTEP*1.1895841f,  KSTEP*1.0116009f,
        KSTEP*0.8472979f,  KSTEP*0.6931472f,  KSTEP*0.5465437f,  KSTEP*0.4054651f,
        KSTEP*0.2682640f,  KSTEP*0.1335314f,  0.0f,
        -KSTEP*0.1335314f, -KSTEP*0.2682640f, -KSTEP*0.4054651f, -KSTEP*0.5465437f,
        -KSTEP*0.6931472f, -KSTEP*0.8472979f, -KSTEP*1.0116009f, -KSTEP*1.1895841f,
        -KSTEP*1.3862944f, -KSTEP*1.6094379f, -KSTEP*1.8718022f, -KSTEP*2.1972246f,
        -KSTEP*2.6390573f, -KSTEP*3.3673323f };

    f16x2 cnt[15], sum[15];
    #pragma unroll
    for (int p = 0; p < 15; ++p) {
        cnt[p] = (f16x2){(__fp16)0.0f, (__fp16)0.0f};
        sum[p] = (f16x2){(__fp16)0.0f, (__fp16)0.0f};
    }

    const int tid = threadIdx.x;

    auto proc = [&](float x, float tt) {
        float y   = __builtin_fmaf(x * tt, -2.0f, x);        // t ? -x : x
        float yk  = y * KSTEP;
        float e   = fast_exp2(fabsf(y) * -LOG2E);            // exp(-|y|)
        float bce = fmaxf(y, 0.0f) + fast_log2(1.0f + e) * LN2;
        f16x2 bce2 = __builtin_amdgcn_cvt_pkrtz(bce, bce);
        #pragma unroll
        for (int p = 0; p < 15; ++p) {
            float s0, s1;
            asm("v_add_f32 %0, %1, %2 clamp" : "=v"(s0) : "s"(nthr[2*p]),   "v"(yk));
            asm("v_add_f32 %0, %1, %2 clamp" : "=v"(s1) : "s"(nthr[2*p+1]), "v"(yk));
            f16x2 s2 = __builtin_amdgcn_cvt_pkrtz(s0, s1);
            cnt[p] += s2;                                    // v_pk_add_f16
            sum[p] += s2 * bce2;                             // v_pk_fma_f16
        }
    };

    const long stride = (long)gridDim.x * BLOCK;
    for (long i = (long)blockIdx.x * BLOCK + tid; i < n4; i += stride) {
        float4 p = preds4[i];
        float4 t = targets4[i];
        #pragma unroll
        for (int j = 0; j < 4; ++j) proc((&p.x)[j], (&t.x)[j]);
    }

    // scalar tail (n_total % 4; zero for this shape) — block 0 only
    long tail0 = n4 * 4;
    if (blockIdx.x == 0 && tail0 + tid < n_total) {
        proc(((const float*)preds4)[tail0 + tid],
             ((const float*)targets4)[tail0 + tid]);
    }

    // ---- merge: unpack to f32, wave butterfly, LDS, 60 padded atomics ----
    __shared__ float sC[4][BINS];
    __shared__ float sS[4][BINS];
    const int lane = tid & 63, wave = tid >> 6;

    #pragma unroll
    for (int p = 0; p < 15; ++p) {
        float c0 = (float)cnt[p][0], c1 = (float)cnt[p][1];
        float s0 = (float)sum[p][0], s1 = (float)sum[p][1];
        #pragma unroll
        for (int m = 32; m >= 1; m >>= 1) {
            c0 += __shfl_xor(c0, m);  c1 += __shfl_xor(c1, m);
            s0 += __shfl_xor(s0, m);  s1 += __shfl_xor(s1, m);
        }
        if (lane == 0) {
            sC[wave][2*p] = c0;  sC[wave][2*p+1] = c1;
            sS[wave][2*p] = s0;  sS[wave][2*p+1] = s1;
        }
    }
    __syncthreads();

    if (tid < BINS) {
        float c = sC[0][tid] + sC[1][tid] + sC[2][tid] + sC[3][tid];
        float s = sS[0][tid] + sS[1][tid] + sS[2][tid] + sS[3][tid];
        atomicAdd(&gCnt[tid * GSTRIDE], c);
        atomicAdd(&gSum[tid * GSTRIDE], s);
    }
}

// cnt_b = C_b - C_{b+1}, S_b = S_cum_b - S_cum_{b+1} (C_30 = S_30 = 0).
// loss = (1/n) * sum_b S_b / (0.75*acc_b + 0.25*cnt_b), n = max(#populated,1)
__global__ void ghm_final(const float* __restrict__ gCnt,
                          const float* __restrict__ gSum,
                          const float* __restrict__ acc_sum,
                          float* __restrict__ out)
{
    int b = threadIdx.x;
    float val = 0.0f, nz = 0.0f;
    if (b < BINS) {
        float Cb  = gCnt[b * GSTRIDE];
        float Cb1 = (b < 29) ? gCnt[(b + 1) * GSTRIDE] : 0.0f;
        float cb  = Cb - Cb1;
        if (cb > 0.5f) {   // counts are (near-)integers; 0.5 kills soft-zone dust
            float Sb = gSum[b * GSTRIDE] - ((b < 29) ? gSum[(b + 1) * GSTRIDE] : 0.0f);
            float na = 0.75f * acc_sum[b] + 0.25f * cb;
            val = Sb / na;
            nz  = 1.0f;
        }
    }
    #pragma unroll
    for (int m = 32; m >= 1; m >>= 1) {
        val += __shfl_xor(val, m);
        nz  += __shfl_xor(nz,  m);
    }
    if (b == 0) out[0] = val / fmaxf(nz, 1.0f);
}

extern "C" void kernel_launch(void* const* d_in, const int* in_sizes, int n_in,
                              void* d_out, int out_size, void* d_ws, size_t ws_size,
                              hipStream_t stream)
{
    const float* preds   = (const float*)d_in[0];
    const float* targets = (const float*)d_in[1];
    const float* acc_sum = (const float*)d_in[2];

    float* gCnt = (float*)d_ws;                 // slots 0..29, stride GSTRIDE
    float* gSum = gCnt + BINS * GSTRIDE;        // slots 0..29, stride GSTRIDE

    long n  = (long)in_sizes[0];
    long n4 = n / 4;

    // ws poisoned once, never re-poisoned: zero accumulators every call
    hipMemsetAsync(d_ws, 0, 2 * BINS * GSTRIDE * sizeof(float), stream);

    long want = (n4 + BLOCK - 1) / BLOCK;
    int blocks = (int)((want < GRID) ? (want > 1 ? want : 1) : GRID);

    ghm_pass1<<<blocks, BLOCK, 0, stream>>>((const float4*)preds,
                                            (const float4*)targets,
                                            n4, n, gCnt, gSum);
    ghm_final<<<1, 64, 0, stream>>>(gCnt, gSum, acc_sum, (float*)d_out);
}

// Round 9
// 53.439 us; speedup vs baseline: 1.1907x; 1.1907x over previous
//
#include <hip/hip_runtime.h>

#define BINS 30
#define NTHR 29
#define BLOCK 256
#define GRID 1024           // 4 blocks/CU x 4 waves = 16 waves/CU (VGPR<=128)
#define GSTRIDE 32          // one 128B cache line per global accumulator slot
#define KSCALE 2048.0f

// __builtin_amdgcn_cvt_pkrtz returns __fp16 ext_vector(2)
typedef __fp16 f16x2 __attribute__((ext_vector_type(2)));

__device__ __forceinline__ float fast_exp2(float x){ return __builtin_amdgcn_exp2f(x); }
__device__ __forceinline__ float fast_log2(float x){ return __builtin_amdgcn_logf(x); }

#define LOG2E 1.4426950408889634f
#define LN2   0.6931471805599453f

// dup'd f16 bit pattern of (float v), both halves — constant-folded at -O3
__device__ __forceinline__ unsigned packdup(float v) {
    __fp16 h = (__fp16)v;
    unsigned short u = __builtin_bit_cast(unsigned short, h);
    return ((unsigned)u << 16) | u;
}

// Cumulative-threshold GHM (no LDS / no atomics in hot loop):
//   y = t ? -x : x;  g = sigmoid(y);  bin(y) = #{k in 1..29 : y >= logit(k/30)}
//   bce = max(y,0) + log1p(exp(-|y|))
// Two ELEMENTS packed per f16x2; per threshold k: ONE v_pk_add_f16 clamp
// (packed step), ONE v_pk_add_f16 (count), ONE v_pk_fma_f16 (bce sum).
// C_0 = N is known analytically; S_cum_0 accumulates as one packed add.
__global__ __launch_bounds__(BLOCK, 4) void ghm_pass1(
    const float4* __restrict__ preds4, const float4* __restrict__ targets4,
    long n4, long n_total,
    float* __restrict__ gC, float* __restrict__ gS)   // padded slots 0..29
{
    // -KSCALE * logit(k/30), k=1..29, packed f16 duplicated (SGPR-resident)
    const unsigned nthr[NTHR] = {
        packdup(KSCALE*3.3673323f),  packdup(KSCALE*2.6390573f),
        packdup(KSCALE*2.1972246f),  packdup(KSCALE*1.8718022f),
        packdup(KSCALE*1.6094379f),  packdup(KSCALE*1.3862944f),
        packdup(KSCALE*1.1895841f),  packdup(KSCALE*1.0116009f),
        packdup(KSCALE*0.8472979f),  packdup(KSCALE*0.6931472f),
        packdup(KSCALE*0.5465437f),  packdup(KSCALE*0.4054651f),
        packdup(KSCALE*0.2682640f),  packdup(KSCALE*0.1335314f),
        0u,
        packdup(-KSCALE*0.1335314f), packdup(-KSCALE*0.2682640f),
        packdup(-KSCALE*0.4054651f), packdup(-KSCALE*0.5465437f),
        packdup(-KSCALE*0.6931472f), packdup(-KSCALE*0.8472979f),
        packdup(-KSCALE*1.0116009f), packdup(-KSCALE*1.1895841f),
        packdup(-KSCALE*1.3862944f), packdup(-KSCALE*1.6094379f),
        packdup(-KSCALE*1.8718022f), packdup(-KSCALE*2.1972246f),
        packdup(-KSCALE*2.6390573f), packdup(-KSCALE*3.3673323f) };

    f16x2 cnt[NTHR], sum[NTHR], s0acc;
    #pragma unroll
    for (int k = 0; k < NTHR; ++k) {
        cnt[k] = (f16x2){(__fp16)0.0f, (__fp16)0.0f};
        sum[k] = (f16x2){(__fp16)0.0f, (__fp16)0.0f};
    }
    s0acc = (f16x2){(__fp16)0.0f, (__fp16)0.0f};

    const int tid = threadIdx.x;

    auto pair = [&](float x0, float t0, float x1, float t1) {
        float y0 = __builtin_fmaf(x0 * t0, -2.0f, x0);       // t ? -x : x
        float y1 = __builtin_fmaf(x1 * t1, -2.0f, x1);
        f16x2 yk2 = __builtin_amdgcn_cvt_pkrtz(y0 * KSCALE, y1 * KSCALE);
        float e0 = fast_exp2(fabsf(y0) * -LOG2E);            // exp(-|y|)
        float e1 = fast_exp2(fabsf(y1) * -LOG2E);
        float b0 = fmaxf(y0, 0.0f) + fast_log2(1.0f + e0) * LN2;
        float b1 = fmaxf(y1, 0.0f) + fast_log2(1.0f + e1) * LN2;
        f16x2 bce2 = __builtin_amdgcn_cvt_pkrtz(b0, b1);
        s0acc += bce2;
        #pragma unroll
        for (int k = 0; k < NTHR; ++k) {
            f16x2 s2;
            asm("v_pk_add_f16 %0, %1, %2 clamp"
                : "=v"(s2) : "v"(yk2), "s"(nthr[k]));        // packed step fn
            cnt[k] += s2;                                    // v_pk_add_f16
            sum[k] += s2 * bce2;                             // v_pk_fma_f16
        }
    };

    const long stride = (long)gridDim.x * BLOCK;
    for (long i = (long)blockIdx.x * BLOCK + tid; i < n4; i += stride) {
        float4 p = preds4[i];
        float4 t = targets4[i];
        pair(p.x, t.x, p.y, t.y);
        pair(p.z, t.z, p.w, t.w);
    }

    // tail (n_total % 4; zero for this shape): dummy second element y=-1e9
    // contributes exactly 0 to every slot (all steps 0, bce 0)
    long tail0 = n4 * 4;
    if (blockIdx.x == 0 && tail0 + tid < n_total) {
        pair(((const float*)preds4)[tail0 + tid],
             ((const float*)targets4)[tail0 + tid], -1e9f, 0.0f);
    }

    // ---- merge: packed f16x2 wave butterfly (counts stay exact), lane0
    // writes packed words to LDS, then 59 padded global atomics per block ----
    __shared__ unsigned sh[4][2 * NTHR + 1];
    const int lane = tid & 63, wave = tid >> 6;

    #pragma unroll
    for (int k = 0; k < NTHR; ++k) {
        f16x2 c = cnt[k], s = sum[k];
        #pragma unroll
        for (int m = 32; m >= 1; m >>= 1) {
            c += __builtin_bit_cast(f16x2, __shfl_xor(__builtin_bit_cast(int, c), m));
            s += __builtin_bit_cast(f16x2, __shfl_xor(__builtin_bit_cast(int, s), m));
        }
        if (lane == 0) {
            sh[wave][k]        = __builtin_bit_cast(unsigned, c);
            sh[wave][NTHR + k] = __builtin_bit_cast(unsigned, s);
        }
    }
    {
        f16x2 s = s0acc;
        #pragma unroll
        for (int m = 32; m >= 1; m >>= 1)
            s += __builtin_bit_cast(f16x2, __shfl_xor(__builtin_bit_cast(int, s), m));
        if (lane == 0) sh[wave][2 * NTHR] = __builtin_bit_cast(unsigned, s);
    }
    __syncthreads();

    if (tid < 2 * NTHR + 1) {
        float v = 0.0f;
        #pragma unroll
        for (int w = 0; w < 4; ++w) {
            f16x2 h = __builtin_bit_cast(f16x2, sh[w][tid]);
            v += (float)h[0] + (float)h[1];
        }
        if (tid < NTHR)           atomicAdd(&gC[(tid + 1) * GSTRIDE], v);        // C_1..C_29
        else if (tid < 2 * NTHR)  atomicAdd(&gS[(tid - NTHR + 1) * GSTRIDE], v); // S_1..S_29
        else                      atomicAdd(&gS[0], v);                          // S_cum_0
    }
}

// cnt_b = C_b - C_{b+1} (C_0 = tot, C_30 = 0); S_b = Scum_b - Scum_{b+1}.
// loss = (1/n) * sum_b S_b / (0.75*acc_b + 0.25*cnt_b), n = max(#populated,1)
__global__ void ghm_final(const float* __restrict__ gC,
                          const float* __restrict__ gS,
                          const float* __restrict__ acc_sum,
                          float* __restrict__ out, float tot)
{
    int b = threadIdx.x;
    float val = 0.0f, nz = 0.0f;
    if (b < BINS) {
        float Cb  = (b == 0) ? tot : gC[b * GSTRIDE];
        float Cb1 = (b < NTHR) ? gC[(b + 1) * GSTRIDE] : 0.0f;
        float cb  = Cb - Cb1;
        if (cb > 0.5f) {   // soft-zone dust guard
            float Sb = gS[b * GSTRIDE] - ((b < NTHR) ? gS[(b + 1) * GSTRIDE] : 0.0f);
            float na = 0.75f * acc_sum[b] + 0.25f * cb;
            val = Sb / na;
            nz  = 1.0f;
        }
    }
    #pragma unroll
    for (int m = 32; m >= 1; m >>= 1) {
        val += __shfl_xor(val, m);
        nz  += __shfl_xor(nz,  m);
    }
    if (b == 0) out[0] = val / fmaxf(nz, 1.0f);
}

extern "C" void kernel_launch(void* const* d_in, const int* in_sizes, int n_in,
                              void* d_out, int out_size, void* d_ws, size_t ws_size,
                              hipStream_t stream)
{
    const float* preds   = (const float*)d_in[0];
    const float* targets = (const float*)d_in[1];
    const float* acc_sum = (const float*)d_in[2];

    float* gC = (float*)d_ws;                   // slots 0..29 (slot 0 unused)
    float* gS = gC + BINS * GSTRIDE;            // slots 0..29

    long n  = (long)in_sizes[0];
    long n4 = n / 4;

    // ws poisoned once, never re-poisoned: zero accumulators every call
    hipMemsetAsync(d_ws, 0, 2 * BINS * GSTRIDE * sizeof(float), stream);

    long want = (n4 + BLOCK - 1) / BLOCK;
    int blocks = (int)((want < GRID) ? (want > 1 ? want : 1) : GRID);

    ghm_pass1<<<blocks, BLOCK, 0, stream>>>((const float4*)preds,
                                            (const float4*)targets,
                                            n4, n, gC, gS);
    ghm_final<<<1, 64, 0, stream>>>(gC, gS, acc_sum, (float*)d_out, (float)n);
}